// Round 3
// baseline (2683.507 us; speedup 1.0000x reference)
//
#include <hip/hip_runtime.h>

#define T_STEPS 256
#define BATCH   128
#define DIM     1024
#define NROWS   (T_STEPS * BATCH)        // 32768 qx rows
#define TOTROWS (NROWS + 2 * BATCH)      // + hx, cx broadcast rows = 33024
#define NW      1023                     // worker waves (256 blocks * 4 - rec wave)

// ws float-offset layout (ints live in the first words)
#define WS_QDONE 0        // int[256]
#define WS_HDONE 256      // int[256]
#define WS_MCNT  512      // int
#define WS_VCNT  513      // int
#define WS_M     1024     // float[4*1024]
#define WS_V     5120     // float[4]   (own 128B line)
#define WS_CB    5152     // float[4]   (own 128B line)
#define WS_ZERO_BYTES ((WS_CB + 4) * 4)  // memset range covers flags+M+v+cb
#define WS_QX    8192     // float4[32768] = float[131072]
#define WS_HSEQ  (WS_QX + 4 * NROWS)     // float[32768]
#define WS_CFIN  (WS_HSEQ + NROWS)       // float[128]

__device__ __forceinline__ int aload_acq(int* p) {
    return __hip_atomic_load(p, __ATOMIC_ACQUIRE, __HIP_MEMORY_SCOPE_AGENT);
}
__device__ __forceinline__ void ainc_rel(int* p) {
    __hip_atomic_fetch_add(p, 1, __ATOMIC_RELEASE, __HIP_MEMORY_SCOPE_AGENT);
}
__device__ __forceinline__ void astore_rel(int* p, int v) {
    __hip_atomic_store(p, v, __ATOMIC_RELEASE, __HIP_MEMORY_SCOPE_AGENT);
}

__device__ __forceinline__ float fast_tanh(float x) {
    float e = __expf(2.f * x);
    return (e - 1.f) * __builtin_amdgcn_rcpf(e + 1.f);
}

// one recurrence step for one batch element (analytic quantum-gate collapse)
__device__ __forceinline__ void rec_step(float4 q,
                                         float b0, float b1, float b2, float b3,
                                         float v0, float v1, float v2, float v3,
                                         float& h, float& c) {
    float z0 = __cosf(q.x + b0 + h * v0);
    float z1 = __cosf(q.y + b1 + h * v1);
    float z2 = __cosf(q.z + b2 + h * v2);
    float z3 = __cosf(q.w + b3 + h * v3);
    float e1 = z0 * z1;
    float e2 = e1 * z2;
    float e3 = e2 * z3;
    float e0 = z1 * z2 * z3;
    float x0 = __expf(e0), x1 = __expf(e1), x2 = __expf(e2), x3 = __expf(e3);
    float inv = __builtin_amdgcn_rcpf(x0 + x1 + x2 + x3);
    float f  = x0 * inv;
    float i_ = x1 * inv;
    float g  = x2 * inv;
    float o  = x3 * inv;
    c = f * c + i_ * fast_tanh(g);
    h = o * fast_tanh(c);
}

__global__ __launch_bounds__(256, 1) void k_fused(
        const float* __restrict__ x,   const float* __restrict__ Wi,
        const float* __restrict__ bi,  const float* __restrict__ Wh,
        const float* __restrict__ bh,  const float* __restrict__ Wq,
        const float* __restrict__ bq,  const float* __restrict__ theta,
        float* __restrict__ out,       float* __restrict__ wsF) {
    int blk  = blockIdx.x;
    int tid  = threadIdx.x;
    int wave = tid >> 6;
    int lane = tid & 63;

    int*    wsI   = (int*)wsF;
    int*    qdone = wsI + WS_QDONE;
    int*    hdone = wsI + WS_HDONE;
    int*    mcnt  = wsI + WS_MCNT;
    int*    vcnt  = wsI + WS_VCNT;
    float*  M     = wsF + WS_M;
    float*  v     = wsF + WS_V;
    float*  cb    = wsF + WS_CB;
    float4* qx4   = (float4*)(wsF + WS_QX);
    float*  hseq  = wsF + WS_HSEQ;
    float*  cfin  = wsF + WS_CFIN;

    // ---------------- prep ----------------
    if (blk < 64) {
        // M = Wq @ Wi partials: this block covers j in [blk*16, blk*16+16)
        int j0 = blk * 16;
        #pragma unroll
        for (int db = 0; db < 4; db++) {
            int d = db * 256 + tid;
            float a0 = 0.f, a1 = 0.f, a2 = 0.f, a3 = 0.f;
            #pragma unroll 4
            for (int jj = 0; jj < 16; jj++) {
                int j = j0 + jj;
                float wv = Wi[(size_t)j * DIM + d];      // coalesced 1KB/instr
                a0 += Wq[0 * DIM + j] * wv;
                a1 += Wq[1 * DIM + j] * wv;
                a2 += Wq[2 * DIM + j] * wv;
                a3 += Wq[3 * DIM + j] * wv;
            }
            unsafeAtomicAdd(&M[0 * DIM + d], a0);        // HW fp32 atomic
            unsafeAtomicAdd(&M[1 * DIM + d], a1);
            unsafeAtomicAdd(&M[2 * DIM + d], a2);
            unsafeAtomicAdd(&M[3 * DIM + d], a3);
        }
        __syncthreads();                                  // drain block's atomics
        if (tid == 0) ainc_rel(mcnt);
    } else if (blk < 128) {
        // Wh rowsums -> v, cb contributions; per wave 4 rows, no barriers
        int j0 = (blk - 64) * 16 + wave * 4;
        float sv0 = 0.f, sv1 = 0.f, sv2 = 0.f, sv3 = 0.f;
        float sc0 = 0.f, sc1 = 0.f, sc2 = 0.f, sc3 = 0.f;
        for (int jj = 0; jj < 4; jj++) {
            int j = j0 + jj;
            const float4* row = (const float4*)(Wh + (size_t)j * DIM);
            float s = 0.f;
            #pragma unroll
            for (int k = 0; k < 4; k++) {
                float4 t4 = row[k * 64 + lane];
                s += t4.x + t4.y + t4.z + t4.w;
            }
            #pragma unroll
            for (int off = 32; off; off >>= 1) s += __shfl_xor(s, off, 64);
            float bb = bi[j] + bh[j];                    // broadcast loads
            float q0 = Wq[0 * DIM + j], q1 = Wq[1 * DIM + j];
            float q2 = Wq[2 * DIM + j], q3 = Wq[3 * DIM + j];
            sv0 += q0 * s;  sc0 += q0 * bb;
            sv1 += q1 * s;  sc1 += q1 * bb;
            sv2 += q2 * s;  sc2 += q2 * bb;
            sv3 += q3 * s;  sc3 += q3 * bb;
        }
        if (lane == 0) {
            unsafeAtomicAdd(&v[0], sv0);  unsafeAtomicAdd(&v[1], sv1);
            unsafeAtomicAdd(&v[2], sv2);  unsafeAtomicAdd(&v[3], sv3);
            unsafeAtomicAdd(&cb[0], sc0); unsafeAtomicAdd(&cb[1], sc1);
            unsafeAtomicAdd(&cb[2], sc2); unsafeAtomicAdd(&cb[3], sc3);
            ainc_rel(vcnt);                               // release: after adds
        }
    }

    bool isrec = (blk == 255 && wave == 0);

    if (!isrec) {
        // ---------------- qx production ----------------
        while (aload_acq(mcnt) < 64) __builtin_amdgcn_s_sleep(8);

        float4 m[4][4];                                   // M fragment in regs
        #pragma unroll
        for (int w = 0; w < 4; w++)
            #pragma unroll
            for (int k = 0; k < 4; k++)
                m[w][k] = *(const float4*)(M + w * DIM + k * 256 + lane * 4);

        int W = (blk < 255) ? blk * 4 + wave : 1020 + (wave - 1);

        for (int r = W; r < NROWS; r += NW) {
            const float4* row = (const float4*)(x + (size_t)r * DIM);
            float a0 = 0.f, a1 = 0.f, a2 = 0.f, a3 = 0.f;
            #pragma unroll
            for (int k = 0; k < 4; k++) {
                float4 xv = row[k * 64 + lane];
                a0 += xv.x * m[0][k].x + xv.y * m[0][k].y + xv.z * m[0][k].z + xv.w * m[0][k].w;
                a1 += xv.x * m[1][k].x + xv.y * m[1][k].y + xv.z * m[1][k].z + xv.w * m[1][k].w;
                a2 += xv.x * m[2][k].x + xv.y * m[2][k].y + xv.z * m[2][k].z + xv.w * m[2][k].w;
                a3 += xv.x * m[3][k].x + xv.y * m[3][k].y + xv.z * m[3][k].z + xv.w * m[3][k].w;
            }
            #pragma unroll
            for (int off = 32; off; off >>= 1) {
                a0 += __shfl_xor(a0, off, 64);
                a1 += __shfl_xor(a1, off, 64);
                a2 += __shfl_xor(a2, off, 64);
                a3 += __shfl_xor(a3, off, 64);
            }
            if (lane == 0) {
                qx4[r] = make_float4(a0, a1, a2, a3);
                ainc_rel(&qdone[r >> 7]);                 // release covers the store
            }
        }

        // ---------------- broadcast writes (chase hdone) ----------------
        for (int r = W; r < TOTROWS; r += NW) {
            int t = (r < NROWS) ? (r >> 7) : (T_STEPS - 1);
            while (aload_acq(&hdone[t]) == 0) __builtin_amdgcn_s_sleep(1);
            float val;
            if      (r < NROWS)          val = hseq[r];
            else if (r < NROWS + BATCH)  val = hseq[(T_STEPS - 1) * BATCH + (r - NROWS)];
            else                         val = cfin[r - NROWS - BATCH];
            float4 vv = make_float4(val, val, val, val);
            float4* orow = (float4*)(out + (size_t)r * DIM);
            orow[0 * 64 + lane] = vv;
            orow[1 * 64 + lane] = vv;
            orow[2 * 64 + lane] = vv;
            orow[3 * 64 + lane] = vv;
        }
    } else {
        // ---------------- recurrence (block 255, wave 0) ----------------
        while (aload_acq(vcnt) < 256) __builtin_amdgcn_s_sleep(8);
        float v0 = v[0], v1 = v[1], v2 = v[2], v3 = v[3];
        float b0 = cb[0] + bq[0] + theta[0];
        float b1 = cb[1] + bq[1] + theta[1];
        float b2 = cb[2] + bq[2] + theta[2];
        float b3 = cb[3] + bq[3] + theta[3];

        float h1 = 0.f, c1 = 0.f, h2 = 0.f, c2 = 0.f;     // lane -> b=lane, b=lane+64

        for (int ch = 0; ch < 16; ch++) {
            // wait for all 16 timesteps of this chunk (lane-parallel flag poll)
            for (;;) {
                int fl = aload_acq(&qdone[ch * 16 + (lane & 15)]);
                if (__ballot(fl < BATCH) == 0ull) break;
                __builtin_amdgcn_s_sleep(1);
            }
            int t0 = ch * 16;
            float4 qa = qx4[t0 * BATCH + lane];
            float4 qb = qx4[t0 * BATCH + 64 + lane];
            for (int t = t0; t < t0 + 16; t++) {
                float4 qa_n, qb_n;
                if (t + 1 < t0 + 16) {                    // prefetch within chunk
                    qa_n = qx4[(t + 1) * BATCH + lane];
                    qb_n = qx4[(t + 1) * BATCH + 64 + lane];
                }
                rec_step(qa, b0, b1, b2, b3, v0, v1, v2, v3, h1, c1);
                rec_step(qb, b0, b1, b2, b3, v0, v1, v2, v3, h2, c2);
                hseq[t * BATCH + lane]      = h1;
                hseq[t * BATCH + 64 + lane] = h2;
                if (t == T_STEPS - 1) { cfin[lane] = c1; cfin[64 + lane] = c2; }
                if ((t & 3) == 3 && lane < 4)             // group-of-4 release
                    astore_rel(&hdone[t - 3 + lane], 1);
                qa = qa_n; qb = qb_n;
            }
        }
    }
}

extern "C" void kernel_launch(void* const* d_in, const int* in_sizes, int n_in,
                              void* d_out, int out_size, void* d_ws, size_t ws_size,
                              hipStream_t stream) {
    const float* inputs = (const float*)d_in[0];
    const float* Wi     = (const float*)d_in[1];
    const float* bi     = (const float*)d_in[2];
    const float* Wh     = (const float*)d_in[3];
    const float* bh     = (const float*)d_in[4];
    const float* Wq     = (const float*)d_in[5];
    const float* bq     = (const float*)d_in[6];
    const float* theta  = (const float*)d_in[7];
    float* out = (float*)d_out;
    float* ws  = (float*)d_ws;

    hipMemsetAsync(ws, 0, WS_ZERO_BYTES, stream);  // zero flags + M + v + cb
    k_fused<<<256, 256, 0, stream>>>(inputs, Wi, bi, Wh, bh, Wq, bq, theta, out, ws);
}

// Round 5
// 399.793 us; speedup vs baseline: 6.7122x; 6.7122x over previous
//
#include <hip/hip_runtime.h>

#define T_STEPS 256
#define BATCH   128
#define DIM     1024
#define NROWS   (T_STEPS * BATCH)        // 32768 qx rows
#define TOTROWS (NROWS + 2 * BATCH)      // + hx, cx broadcast rows = 33024

typedef float vfloat4 __attribute__((ext_vector_type(4)));  // for nontemporal builtins

// ws float-offset layout
#define WS_M     0                        // float[4*1024]
#define WS_V     4096                     // float[4]
#define WS_CB    4128                     // float[4]
#define WS_ZERO_BYTES ((WS_CB + 4) * 4)   // memset covers M + v + cb
#define WS_QX    8192                     // float4[32768]
#define WS_HSEQ  (WS_QX + 4 * NROWS)      // float[32768]
#define WS_CFIN  (WS_HSEQ + NROWS)        // float[128]

// ---------- prep (one kernel): M = Wq@Wi via fp32 HW atomics; v/cb via atomics ----------
__global__ __launch_bounds__(256) void k_prep(const float* __restrict__ Wi,
                                              const float* __restrict__ Wh,
                                              const float* __restrict__ bi,
                                              const float* __restrict__ bh,
                                              const float* __restrict__ Wq,
                                              float* __restrict__ wsF) {
    int blk  = blockIdx.x;
    int tid  = threadIdx.x;
    int wave = tid >> 6;
    int lane = tid & 63;
    float* M  = wsF + WS_M;
    float* v  = wsF + WS_V;
    float* cb = wsF + WS_CB;

    if (blk < 64) {
        // M partials: this block covers j in [blk*16, blk*16+16)
        int j0 = blk * 16;
        #pragma unroll
        for (int db = 0; db < 4; db++) {
            int d = db * 256 + tid;
            float a0 = 0.f, a1 = 0.f, a2 = 0.f, a3 = 0.f;
            #pragma unroll 4
            for (int jj = 0; jj < 16; jj++) {
                int j = j0 + jj;
                float wv = Wi[(size_t)j * DIM + d];   // coalesced 1KB/instr
                a0 += Wq[0 * DIM + j] * wv;           // uniform -> scalar loads
                a1 += Wq[1 * DIM + j] * wv;
                a2 += Wq[2 * DIM + j] * wv;
                a3 += Wq[3 * DIM + j] * wv;
            }
            unsafeAtomicAdd(&M[0 * DIM + d], a0);
            unsafeAtomicAdd(&M[1 * DIM + d], a1);
            unsafeAtomicAdd(&M[2 * DIM + d], a2);
            unsafeAtomicAdd(&M[3 * DIM + d], a3);
        }
    } else {
        // Wh rowsums -> v, cb contributions; each wave handles 4 rows
        int j0 = (blk - 64) * 16 + wave * 4;
        float sv0 = 0.f, sv1 = 0.f, sv2 = 0.f, sv3 = 0.f;
        float sc0 = 0.f, sc1 = 0.f, sc2 = 0.f, sc3 = 0.f;
        #pragma unroll
        for (int jj = 0; jj < 4; jj++) {
            int j = j0 + jj;
            const float4* row = (const float4*)(Wh + (size_t)j * DIM);
            float s = 0.f;
            #pragma unroll
            for (int k = 0; k < 4; k++) {
                float4 t4 = row[k * 64 + lane];
                s += t4.x + t4.y + t4.z + t4.w;
            }
            #pragma unroll
            for (int off = 32; off; off >>= 1) s += __shfl_xor(s, off, 64);
            float bb = bi[j] + bh[j];
            float q0 = Wq[0 * DIM + j], q1 = Wq[1 * DIM + j];
            float q2 = Wq[2 * DIM + j], q3 = Wq[3 * DIM + j];
            sv0 += q0 * s;  sc0 += q0 * bb;
            sv1 += q1 * s;  sc1 += q1 * bb;
            sv2 += q2 * s;  sc2 += q2 * bb;
            sv3 += q3 * s;  sc3 += q3 * bb;
        }
        if (lane == 0) {
            unsafeAtomicAdd(&v[0], sv0);  unsafeAtomicAdd(&v[1], sv1);
            unsafeAtomicAdd(&v[2], sv2);  unsafeAtomicAdd(&v[3], sv3);
            unsafeAtomicAdd(&cb[0], sc0); unsafeAtomicAdd(&cb[1], sc1);
            unsafeAtomicAdd(&cb[2], sc2); unsafeAtomicAdd(&cb[3], sc3);
        }
    }
}

// ---------- qx = inputs @ M.T  [T*B, 4] ; wave per row ----------
__global__ __launch_bounds__(256) void k_qx(const float* __restrict__ x,
                                            float* __restrict__ wsF) {
    float* M = wsF + WS_M;
    float4* qx4 = (float4*)(wsF + WS_QX);
    int gtid   = blockIdx.x * blockDim.x + threadIdx.x;
    int wave   = gtid >> 6;
    int lane   = threadIdx.x & 63;
    int nwaves = (gridDim.x * blockDim.x) >> 6;

    float4 m[4][4];                                    // M fragment in regs
    #pragma unroll
    for (int w = 0; w < 4; w++)
        #pragma unroll
        for (int k = 0; k < 4; k++)
            m[w][k] = *(const float4*)(M + w * DIM + k * 256 + lane * 4);

    for (int r = wave; r < NROWS; r += nwaves) {
        const float4* row = (const float4*)(x + (size_t)r * DIM);
        float a0 = 0.f, a1 = 0.f, a2 = 0.f, a3 = 0.f;
        #pragma unroll
        for (int k = 0; k < 4; k++) {
            float4 xv = row[k * 64 + lane];            // contiguous 1 KB/instr
            a0 += xv.x * m[0][k].x + xv.y * m[0][k].y + xv.z * m[0][k].z + xv.w * m[0][k].w;
            a1 += xv.x * m[1][k].x + xv.y * m[1][k].y + xv.z * m[1][k].z + xv.w * m[1][k].w;
            a2 += xv.x * m[2][k].x + xv.y * m[2][k].y + xv.z * m[2][k].z + xv.w * m[2][k].w;
            a3 += xv.x * m[3][k].x + xv.y * m[3][k].y + xv.z * m[3][k].z + xv.w * m[3][k].w;
        }
        #pragma unroll
        for (int off = 32; off; off >>= 1) {
            a0 += __shfl_xor(a0, off, 64);
            a1 += __shfl_xor(a1, off, 64);
            a2 += __shfl_xor(a2, off, 64);
            a3 += __shfl_xor(a3, off, 64);
        }
        if (lane == 0) qx4[r] = make_float4(a0, a1, a2, a3);
    }
}

// ---------- recurrence: 1 wave, 2 batch elems/lane, prefetch depth 2 ----------
__device__ __forceinline__ float fast_tanh(float x) {
    float e = __expf(2.f * x);
    return (e - 1.f) * __builtin_amdgcn_rcpf(e + 1.f);
}

__device__ __forceinline__ void rec_step(float4 q,
                                         float b0, float b1, float b2, float b3,
                                         float v0, float v1, float v2, float v3,
                                         float& h, float& c) {
    float z0 = __cosf(q.x + b0 + h * v0);
    float z1 = __cosf(q.y + b1 + h * v1);
    float z2 = __cosf(q.z + b2 + h * v2);
    float z3 = __cosf(q.w + b3 + h * v3);
    float e1 = z0 * z1;
    float e2 = e1 * z2;
    float e3 = e2 * z3;
    float e0 = z1 * z2 * z3;
    float x0 = __expf(e0), x1 = __expf(e1), x2 = __expf(e2), x3 = __expf(e3);
    float inv = __builtin_amdgcn_rcpf(x0 + x1 + x2 + x3);
    float f  = x0 * inv;
    float i_ = x1 * inv;
    float g  = x2 * inv;
    float o  = x3 * inv;
    c = f * c + i_ * fast_tanh(g);
    h = o * fast_tanh(c);
}

__global__ __launch_bounds__(64) void k_rec(const float* __restrict__ bq,
                                            const float* __restrict__ theta,
                                            float* __restrict__ wsF) {
    const float4* qx4 = (const float4*)(wsF + WS_QX);
    float* v    = wsF + WS_V;
    float* cbp  = wsF + WS_CB;
    float* hseq = wsF + WS_HSEQ;
    float* cfin = wsF + WS_CFIN;
    int lane = threadIdx.x;

    float v0 = v[0], v1 = v[1], v2 = v[2], v3 = v[3];
    float b0 = cbp[0] + bq[0] + theta[0];
    float b1 = cbp[1] + bq[1] + theta[1];
    float b2 = cbp[2] + bq[2] + theta[2];
    float b3 = cbp[3] + bq[3] + theta[3];

    float h1 = 0.f, c1 = 0.f, h2 = 0.f, c2 = 0.f;

    // prefetch pipeline depth 2
    float4 qa0 = qx4[0 * BATCH + lane],      qb0 = qx4[0 * BATCH + 64 + lane];
    float4 qa1 = qx4[1 * BATCH + lane],      qb1 = qx4[1 * BATCH + 64 + lane];
    for (int t = 0; t < T_STEPS; t++) {
        float4 qa2, qb2;
        if (t + 2 < T_STEPS) {
            qa2 = qx4[(t + 2) * BATCH + lane];
            qb2 = qx4[(t + 2) * BATCH + 64 + lane];
        }
        rec_step(qa0, b0, b1, b2, b3, v0, v1, v2, v3, h1, c1);
        rec_step(qb0, b0, b1, b2, b3, v0, v1, v2, v3, h2, c2);
        hseq[t * BATCH + lane]      = h1;
        hseq[t * BATCH + 64 + lane] = h2;
        qa0 = qa1; qb0 = qb1; qa1 = qa2; qb1 = qb2;
    }
    cfin[lane]      = c1;
    cfin[64 + lane] = c2;
}

// ---------- broadcast write: 4 rows per block, nontemporal ----------
__global__ __launch_bounds__(256) void k_write(const float* __restrict__ wsF,
                                               float* __restrict__ out) {
    const float* hseq = wsF + WS_HSEQ;
    const float* cfin = wsF + WS_CFIN;
    int tid  = threadIdx.x;
    int r    = blockIdx.x * 4 + (tid >> 6);   // this thread's row
    int lane = tid & 63;

    float val;
    if      (r < NROWS)          val = hseq[r];
    else if (r < NROWS + BATCH)  val = hseq[(T_STEPS - 1) * BATCH + (r - NROWS)];
    else                         val = cfin[r - NROWS - BATCH];

    vfloat4 vv = {val, val, val, val};
    vfloat4* orow = (vfloat4*)(out + (size_t)r * DIM);
    __builtin_nontemporal_store(vv, &orow[0 * 64 + lane]);
    __builtin_nontemporal_store(vv, &orow[1 * 64 + lane]);
    __builtin_nontemporal_store(vv, &orow[2 * 64 + lane]);
    __builtin_nontemporal_store(vv, &orow[3 * 64 + lane]);
}

extern "C" void kernel_launch(void* const* d_in, const int* in_sizes, int n_in,
                              void* d_out, int out_size, void* d_ws, size_t ws_size,
                              hipStream_t stream) {
    const float* inputs = (const float*)d_in[0];
    const float* Wi     = (const float*)d_in[1];
    const float* bi     = (const float*)d_in[2];
    const float* Wh     = (const float*)d_in[3];
    const float* bh     = (const float*)d_in[4];
    const float* Wq     = (const float*)d_in[5];
    const float* bq     = (const float*)d_in[6];
    const float* theta  = (const float*)d_in[7];
    float* out = (float*)d_out;
    float* ws  = (float*)d_ws;

    (void)hipMemsetAsync(ws, 0, WS_ZERO_BYTES, stream);    // zero M + v + cb
    k_prep <<<128,  256, 0, stream>>>(Wi, Wh, bi, bh, Wq, ws);
    k_qx   <<<1024, 256, 0, stream>>>(inputs, ws);
    k_rec  <<<1,     64, 0, stream>>>(bq, theta, ws);
    k_write<<<TOTROWS / 4, 256, 0, stream>>>(ws, out);
}

// Round 6
// 314.127 us; speedup vs baseline: 8.5427x; 1.2727x over previous
//
#include <hip/hip_runtime.h>

#define T_STEPS 256
#define BATCH   128
#define DIM     1024
#define NROWS   (T_STEPS * BATCH)        // 32768 qx rows
#define TOTROWS (NROWS + 2 * BATCH)      // + hx, cx broadcast rows = 33024

typedef float vfloat4 __attribute__((ext_vector_type(4)));  // for nontemporal builtins

// ws float-offset layout
#define WS_M     0                        // float[4*1024]
#define WS_V     4096                     // float[4]
#define WS_CB    4128                     // float[4]
#define WS_ZERO_BYTES ((WS_CB + 4) * 4)   // memset covers M + v + cb
#define WS_QX    8192                     // float4[32768]
#define WS_HSEQ  (WS_QX + 4 * NROWS)      // float[32768]
#define WS_CFIN  (WS_HSEQ + NROWS)        // float[128]

// ---------- prep (one kernel): M = Wq@Wi via fp32 HW atomics; v/cb via atomics ----------
__global__ __launch_bounds__(256) void k_prep(const float* __restrict__ Wi,
                                              const float* __restrict__ Wh,
                                              const float* __restrict__ bi,
                                              const float* __restrict__ bh,
                                              const float* __restrict__ Wq,
                                              float* __restrict__ M,
                                              float* __restrict__ v,
                                              float* __restrict__ cb) {
    int blk  = blockIdx.x;
    int tid  = threadIdx.x;
    int wave = tid >> 6;
    int lane = tid & 63;

    if (blk < 64) {
        // M partials: this block covers j in [blk*16, blk*16+16)
        int j0 = blk * 16;
        #pragma unroll
        for (int db = 0; db < 4; db++) {
            int d = db * 256 + tid;
            float a0 = 0.f, a1 = 0.f, a2 = 0.f, a3 = 0.f;
            #pragma unroll 4
            for (int jj = 0; jj < 16; jj++) {
                int j = j0 + jj;
                float wv = Wi[(size_t)j * DIM + d];   // coalesced 1KB/instr
                a0 += Wq[0 * DIM + j] * wv;           // uniform -> scalar loads
                a1 += Wq[1 * DIM + j] * wv;
                a2 += Wq[2 * DIM + j] * wv;
                a3 += Wq[3 * DIM + j] * wv;
            }
            unsafeAtomicAdd(&M[0 * DIM + d], a0);
            unsafeAtomicAdd(&M[1 * DIM + d], a1);
            unsafeAtomicAdd(&M[2 * DIM + d], a2);
            unsafeAtomicAdd(&M[3 * DIM + d], a3);
        }
    } else {
        // Wh rowsums -> v, cb contributions; each wave handles 4 rows
        int j0 = (blk - 64) * 16 + wave * 4;
        float sv0 = 0.f, sv1 = 0.f, sv2 = 0.f, sv3 = 0.f;
        float sc0 = 0.f, sc1 = 0.f, sc2 = 0.f, sc3 = 0.f;
        #pragma unroll
        for (int jj = 0; jj < 4; jj++) {
            int j = j0 + jj;
            const float4* row = (const float4*)(Wh + (size_t)j * DIM);
            float s = 0.f;
            #pragma unroll
            for (int k = 0; k < 4; k++) {
                float4 t4 = row[k * 64 + lane];
                s += t4.x + t4.y + t4.z + t4.w;
            }
            #pragma unroll
            for (int off = 32; off; off >>= 1) s += __shfl_xor(s, off, 64);
            float bb = bi[j] + bh[j];
            float q0 = Wq[0 * DIM + j], q1 = Wq[1 * DIM + j];
            float q2 = Wq[2 * DIM + j], q3 = Wq[3 * DIM + j];
            sv0 += q0 * s;  sc0 += q0 * bb;
            sv1 += q1 * s;  sc1 += q1 * bb;
            sv2 += q2 * s;  sc2 += q2 * bb;
            sv3 += q3 * s;  sc3 += q3 * bb;
        }
        if (lane == 0) {
            unsafeAtomicAdd(&v[0], sv0);  unsafeAtomicAdd(&v[1], sv1);
            unsafeAtomicAdd(&v[2], sv2);  unsafeAtomicAdd(&v[3], sv3);
            unsafeAtomicAdd(&cb[0], sc0); unsafeAtomicAdd(&cb[1], sc1);
            unsafeAtomicAdd(&cb[2], sc2); unsafeAtomicAdd(&cb[3], sc3);
        }
    }
}

// ---------- qx = inputs @ M.T  [T*B, 4] ; wave per row ----------
__global__ __launch_bounds__(256) void k_qx(const float* __restrict__ x,
                                            const float* __restrict__ M,
                                            float4* __restrict__ qx4) {
    int gtid   = blockIdx.x * blockDim.x + threadIdx.x;
    int wave   = gtid >> 6;
    int lane   = threadIdx.x & 63;
    int nwaves = (gridDim.x * blockDim.x) >> 6;

    float4 m[4][4];                                    // M fragment in regs
    #pragma unroll
    for (int w = 0; w < 4; w++)
        #pragma unroll
        for (int k = 0; k < 4; k++)
            m[w][k] = *(const float4*)(M + w * DIM + k * 256 + lane * 4);

    for (int r = wave; r < NROWS; r += nwaves) {
        const float4* row = (const float4*)(x + (size_t)r * DIM);
        float a0 = 0.f, a1 = 0.f, a2 = 0.f, a3 = 0.f;
        #pragma unroll
        for (int k = 0; k < 4; k++) {
            float4 xv = row[k * 64 + lane];            // contiguous 1 KB/instr
            a0 += xv.x * m[0][k].x + xv.y * m[0][k].y + xv.z * m[0][k].z + xv.w * m[0][k].w;
            a1 += xv.x * m[1][k].x + xv.y * m[1][k].y + xv.z * m[1][k].z + xv.w * m[1][k].w;
            a2 += xv.x * m[2][k].x + xv.y * m[2][k].y + xv.z * m[2][k].z + xv.w * m[2][k].w;
            a3 += xv.x * m[3][k].x + xv.y * m[3][k].y + xv.z * m[3][k].z + xv.w * m[3][k].w;
        }
        #pragma unroll
        for (int off = 32; off; off >>= 1) {
            a0 += __shfl_xor(a0, off, 64);
            a1 += __shfl_xor(a1, off, 64);
            a2 += __shfl_xor(a2, off, 64);
            a3 += __shfl_xor(a3, off, 64);
        }
        if (lane == 0) qx4[r] = make_float4(a0, a1, a2, a3);
    }
}

// ---------- recurrence: 2 waves, 1 batch elem/lane, unroll-8 register prefetch ----------
__device__ __forceinline__ float fast_tanh(float x) {
    float e = __expf(2.f * x);
    return (e - 1.f) * __builtin_amdgcn_rcpf(e + 1.f);
}

__device__ __forceinline__ void rec_step(float4 q,
                                         float b0, float b1, float b2, float b3,
                                         float v0, float v1, float v2, float v3,
                                         float& h, float& c) {
    float z0 = __cosf(q.x + b0 + h * v0);
    float z1 = __cosf(q.y + b1 + h * v1);
    float z2 = __cosf(q.z + b2 + h * v2);
    float z3 = __cosf(q.w + b3 + h * v3);
    float e1 = z0 * z1;
    float e2 = e1 * z2;
    float e3 = e2 * z3;
    float e0 = z1 * z2 * z3;
    float x0 = __expf(e0), x1 = __expf(e1), x2 = __expf(e2), x3 = __expf(e3);
    float inv = __builtin_amdgcn_rcpf(x0 + x1 + x2 + x3);
    float f  = x0 * inv;
    float i_ = x1 * inv;
    float g  = x2 * inv;
    float o  = x3 * inv;
    c = f * c + i_ * fast_tanh(g);
    h = o * fast_tanh(c);
}

__global__ __launch_bounds__(128) void k_rec(const float* __restrict__ bq,
                                             const float* __restrict__ theta,
                                             const float* __restrict__ v,
                                             const float* __restrict__ cbp,
                                             const float4* __restrict__ qx4,
                                             float* __restrict__ hseq,
                                             float* __restrict__ cfin) {
    int b = threadIdx.x;                      // 0..127, one chain per lane

    float v0 = v[0], v1 = v[1], v2 = v[2], v3 = v[3];
    float b0 = cbp[0] + bq[0] + theta[0];
    float b1 = cbp[1] + bq[1] + theta[1];
    float b2 = cbp[2] + bq[2] + theta[2];
    float b3 = cbp[3] + bq[3] + theta[3];

    float h = 0.f, c = 0.f;

    // preload first 8 steps
    float4 q0 = qx4[0 * BATCH + b], q1 = qx4[1 * BATCH + b];
    float4 q2 = qx4[2 * BATCH + b], q3 = qx4[3 * BATCH + b];
    float4 q4 = qx4[4 * BATCH + b], q5 = qx4[5 * BATCH + b];
    float4 q6 = qx4[6 * BATCH + b], q7 = qx4[7 * BATCH + b];

    for (int t = 0; t < T_STEPS; t += 8) {
        float4 n0, n1, n2, n3, n4, n5, n6, n7;
        if (t + 8 < T_STEPS) {                // prefetch next 8 (issued up front)
            n0 = qx4[(t + 8)  * BATCH + b];  n1 = qx4[(t + 9)  * BATCH + b];
            n2 = qx4[(t + 10) * BATCH + b];  n3 = qx4[(t + 11) * BATCH + b];
            n4 = qx4[(t + 12) * BATCH + b];  n5 = qx4[(t + 13) * BATCH + b];
            n6 = qx4[(t + 14) * BATCH + b];  n7 = qx4[(t + 15) * BATCH + b];
        }
        rec_step(q0, b0, b1, b2, b3, v0, v1, v2, v3, h, c); hseq[(t + 0) * BATCH + b] = h;
        rec_step(q1, b0, b1, b2, b3, v0, v1, v2, v3, h, c); hseq[(t + 1) * BATCH + b] = h;
        rec_step(q2, b0, b1, b2, b3, v0, v1, v2, v3, h, c); hseq[(t + 2) * BATCH + b] = h;
        rec_step(q3, b0, b1, b2, b3, v0, v1, v2, v3, h, c); hseq[(t + 3) * BATCH + b] = h;
        rec_step(q4, b0, b1, b2, b3, v0, v1, v2, v3, h, c); hseq[(t + 4) * BATCH + b] = h;
        rec_step(q5, b0, b1, b2, b3, v0, v1, v2, v3, h, c); hseq[(t + 5) * BATCH + b] = h;
        rec_step(q6, b0, b1, b2, b3, v0, v1, v2, v3, h, c); hseq[(t + 6) * BATCH + b] = h;
        rec_step(q7, b0, b1, b2, b3, v0, v1, v2, v3, h, c); hseq[(t + 7) * BATCH + b] = h;
        q0 = n0; q1 = n1; q2 = n2; q3 = n3; q4 = n4; q5 = n5; q6 = n6; q7 = n7;
    }
    cfin[b] = c;
}

// ---------- broadcast write: 4 rows per block, nontemporal ----------
__global__ __launch_bounds__(256) void k_write(const float* __restrict__ hseq,
                                               const float* __restrict__ cfin,
                                               float* __restrict__ out) {
    int tid  = threadIdx.x;
    int r    = blockIdx.x * 4 + (tid >> 6);   // this thread's row
    int lane = tid & 63;

    float val;
    if      (r < NROWS)          val = hseq[r];
    else if (r < NROWS + BATCH)  val = hseq[(T_STEPS - 1) * BATCH + (r - NROWS)];
    else                         val = cfin[r - NROWS - BATCH];

    vfloat4 vv = {val, val, val, val};
    vfloat4* orow = (vfloat4*)(out + (size_t)r * DIM);
    __builtin_nontemporal_store(vv, &orow[0 * 64 + lane]);
    __builtin_nontemporal_store(vv, &orow[1 * 64 + lane]);
    __builtin_nontemporal_store(vv, &orow[2 * 64 + lane]);
    __builtin_nontemporal_store(vv, &orow[3 * 64 + lane]);
}

extern "C" void kernel_launch(void* const* d_in, const int* in_sizes, int n_in,
                              void* d_out, int out_size, void* d_ws, size_t ws_size,
                              hipStream_t stream) {
    const float* inputs = (const float*)d_in[0];
    const float* Wi     = (const float*)d_in[1];
    const float* bi     = (const float*)d_in[2];
    const float* Wh     = (const float*)d_in[3];
    const float* bh     = (const float*)d_in[4];
    const float* Wq     = (const float*)d_in[5];
    const float* bq     = (const float*)d_in[6];
    const float* theta  = (const float*)d_in[7];
    float* out = (float*)d_out;
    float* ws  = (float*)d_ws;

    float*  M    = ws + WS_M;
    float*  v    = ws + WS_V;
    float*  cb   = ws + WS_CB;
    float4* qx4  = (float4*)(ws + WS_QX);
    float*  hseq = ws + WS_HSEQ;
    float*  cfin = ws + WS_CFIN;

    (void)hipMemsetAsync(ws, 0, WS_ZERO_BYTES, stream);    // zero M + v + cb
    k_prep <<<128,  256, 0, stream>>>(Wi, Wh, bi, bh, Wq, M, v, cb);
    k_qx   <<<1024, 256, 0, stream>>>(inputs, M, qx4);
    k_rec  <<<1,    128, 0, stream>>>(bq, theta, v, cb, qx4, hseq, cfin);
    k_write<<<TOTROWS / 4, 256, 0, stream>>>(hseq, cfin, out);
}